// Round 1
// baseline (671.237 us; speedup 1.0000x reference)
//
#include <hip/hip_runtime.h>

#define N_NODES 50000
#define N_EDGES 800000
#define IN_CH 128
#define OUT_CH 64
#define HEADS 8
#define ROW 512  // OUT_CH*HEADS, floats per output row

// monotone float<->uint mapping for atomicMax on floats (incl. negatives)
__device__ __forceinline__ unsigned fmap(float f) {
    unsigned b = __float_as_uint(f);
    return b ^ ((b & 0x80000000u) ? 0xFFFFFFFFu : 0x80000000u);
}
__device__ __forceinline__ float funmap(unsigned u) {
    unsigned b = (u & 0x80000000u) ? (u ^ 0x80000000u) : ~u;
    return __uint_as_float(b);
}

__device__ __forceinline__ float lrelu(float z) {
    return z > 0.0f ? z : 0.2f * z;
}

// Zero head-0 accumulator slots of out, and the two scalar reduction cells.
__global__ __launch_bounds__(256) void zero_head0(float* __restrict__ out,
                                                  unsigned* __restrict__ mu,
                                                  float* __restrict__ Z) {
    int tid = blockIdx.x * 256 + threadIdx.x;
    int n = tid >> 6, c = tid & 63;
    if (n < N_NODES) out[n * ROW + c] = 0.0f;
    if (tid == 0) { *mu = 0u; *Z = 0.0f; }
}

// h = x @ W  -> stored at out[n*ROW + 64 + c]  (head-1 slots, temporary)
// s[n] = h[n] . attn[0:64],  t[n] = h[n] . attn[64:128]
__global__ __launch_bounds__(256) void gemm_st(const float* __restrict__ x,
                                               const float* __restrict__ W,
                                               const float* __restrict__ attn,
                                               float* __restrict__ out,
                                               float* __restrict__ s,
                                               float* __restrict__ t) {
    __shared__ float xs[4][IN_CH];
    const int w = threadIdx.x >> 6;
    const int lane = threadIdx.x & 63;
    const int row = blockIdx.x * 4 + w;           // 50000/4 = 12500 exact
    // stage x row in LDS (wave-private; no barrier needed)
    xs[w][lane]      = x[row * IN_CH + lane];
    xs[w][lane + 64] = x[row * IN_CH + 64 + lane];
    float acc = 0.0f;
#pragma unroll 8
    for (int k = 0; k < IN_CH; ++k)
        acc = fmaf(xs[w][k], W[k * OUT_CH + lane], acc);
    out[row * ROW + 64 + lane] = acc;
    float sv = acc * attn[lane];
    float tv = acc * attn[64 + lane];
#pragma unroll
    for (int off = 32; off > 0; off >>= 1) {
        sv += __shfl_down(sv, off, 64);
        tv += __shfl_down(tv, off, 64);
    }
    if (lane == 0) { s[row] = sv; t[row] = tv; }
}

// pass A: global max of logits
__global__ __launch_bounds__(256) void edge_max(const int* __restrict__ ei,
                                                const int* __restrict__ ej,
                                                const float* __restrict__ s,
                                                const float* __restrict__ t,
                                                unsigned* __restrict__ mu) {
    int e = blockIdx.x * 256 + threadIdx.x;       // 3125*256 = 800000 exact
    float l = lrelu(s[ei[e]] + t[ej[e]]);
#pragma unroll
    for (int off = 32; off > 0; off >>= 1)
        l = fmaxf(l, __shfl_down(l, off, 64));
    if ((threadIdx.x & 63) == 0) atomicMax(mu, fmap(l));
}

// pass B: Z = sum exp(logit - m)
__global__ __launch_bounds__(256) void edge_sumexp(const int* __restrict__ ei,
                                                   const int* __restrict__ ej,
                                                   const float* __restrict__ s,
                                                   const float* __restrict__ t,
                                                   const unsigned* __restrict__ mu,
                                                   float* __restrict__ Z) {
    const float m = funmap(*mu);
    int e = blockIdx.x * 256 + threadIdx.x;
    float v = __expf(lrelu(s[ei[e]] + t[ej[e]]) - m);
#pragma unroll
    for (int off = 32; off > 0; off >>= 1)
        v += __shfl_down(v, off, 64);
    if ((threadIdx.x & 63) == 0) atomicAdd(Z, v);
}

// pass C: per edge, out[ei][c] += alpha * h[ej][c]   (one wave per edge)
__global__ __launch_bounds__(256) void scatter_msg(const int* __restrict__ ei,
                                                   const int* __restrict__ ej,
                                                   const float* __restrict__ s,
                                                   const float* __restrict__ t,
                                                   const unsigned* __restrict__ mu,
                                                   const float* __restrict__ Z,
                                                   float* __restrict__ out) {
    const int e = blockIdx.x * 4 + (threadIdx.x >> 6);  // 200000*4 = 800000 exact
    const int lane = threadIdx.x & 63;
    const float m = funmap(*mu);
    const float invZ = 1.0f / (*Z);
    const int li = ei[e];
    const int lj = ej[e];
    const float alpha = __expf(lrelu(s[li] + t[lj]) - m) * invZ;
    const float hv = out[lj * ROW + 64 + lane];         // h lives in head-1 slots
    atomicAdd(&out[li * ROW + lane], alpha * hv);       // accumulate into head-0
}

// pass D: tile head-0 into heads 1..7 (overwrites the temporary h storage)
__global__ __launch_bounds__(256) void tile_heads(float* __restrict__ out) {
    float4* out4 = (float4*)out;
    const int n = blockIdx.x * 2 + (threadIdx.x >> 7);  // 25000*2 = 50000 exact
    const int j = threadIdx.x & 127;                    // float4 index in heads 1..7
    if (j < 112) {
        float4 v = out4[n * 128 + (j & 15)];            // read head-0
        out4[n * 128 + 16 + j] = v;                     // write heads 1..7
    }
}

extern "C" void kernel_launch(void* const* d_in, const int* in_sizes, int n_in,
                              void* d_out, int out_size, void* d_ws, size_t ws_size,
                              hipStream_t stream) {
    const float* x    = (const float*)d_in[0];
    const int*   eidx = (const int*)d_in[1];
    const float* W    = (const float*)d_in[2];
    const float* attn = (const float*)d_in[3];
    float* out = (float*)d_out;

    float* s = (float*)d_ws;
    float* t = s + N_NODES;
    unsigned* mu = (unsigned*)(t + N_NODES);
    float* Z = (float*)(mu + 1);

    const int* ei = eidx;            // destinations
    const int* ej = eidx + N_EDGES;  // sources

    zero_head0 <<<(N_NODES * 64 + 255) / 256, 256, 0, stream>>>(out, mu, Z);
    gemm_st    <<<N_NODES / 4, 256, 0, stream>>>(x, W, attn, out, s, t);
    edge_max   <<<N_EDGES / 256, 256, 0, stream>>>(ei, ej, s, t, mu);
    edge_sumexp<<<N_EDGES / 256, 256, 0, stream>>>(ei, ej, s, t, mu, Z);
    scatter_msg<<<N_EDGES / 4, 256, 0, stream>>>(ei, ej, s, t, mu, Z, out);
    tile_heads <<<N_NODES / 2, 256, 0, stream>>>(out);
}

// Round 3
// 373.077 us; speedup vs baseline: 1.7992x; 1.7992x over previous
//
#include <hip/hip_runtime.h>

#define N_NODES 50000
#define N_EDGES 800000
#define IN_CH 128
#define OUT_CH 64
#define HEADS 8
#define ROW 512           // OUT_CH*HEADS, floats per output row
#define NBLK_E 3125       // N_EDGES / 256

__device__ __forceinline__ float lrelu(float z) {
    return z > 0.0f ? z : 0.2f * z;
}

// h = x @ W  -> stored at out[n*ROW + 64 + c]  (head-1 slots, temporary)
// s[n] = h[n] . attn[0:64],  t[n] = h[n] . attn[64:128]
// also zeroes the head-0 accumulator slots out[n*ROW + c]
__global__ __launch_bounds__(256) void gemm_st(const float* __restrict__ x,
                                               const float* __restrict__ W,
                                               const float* __restrict__ attn,
                                               float* __restrict__ out,
                                               float* __restrict__ s,
                                               float* __restrict__ t) {
    __shared__ float xs[4][IN_CH];
    const int w = threadIdx.x >> 6;
    const int lane = threadIdx.x & 63;
    const int row = blockIdx.x * 4 + w;           // 50000/4 = 12500 exact
    // stage x row in LDS (wave-private; no barrier needed)
    xs[w][lane]      = x[row * IN_CH + lane];
    xs[w][lane + 64] = x[row * IN_CH + 64 + lane];
    float acc = 0.0f;
#pragma unroll 8
    for (int k = 0; k < IN_CH; ++k)
        acc = fmaf(xs[w][k], W[k * OUT_CH + lane], acc);
    out[row * ROW + lane]      = 0.0f;            // zero head-0 accumulator
    out[row * ROW + 64 + lane] = acc;             // stash h in head-1 slots
    float sv = acc * attn[lane];
    float tv = acc * attn[64 + lane];
#pragma unroll
    for (int off = 32; off > 0; off >>= 1) {
        sv += __shfl_down(sv, off, 64);
        tv += __shfl_down(tv, off, 64);
    }
    if (lane == 0) { s[row] = sv; t[row] = tv; }
}

// one pass: partial[b] = sum over block's edges of exp(leaky_relu(s[ei]+t[ej]))
// (no max subtraction: logits ~ N(0,1), max ~5, exp is safe in fp32; softmax
//  is shift-invariant so the result is identical)
__global__ __launch_bounds__(256) void edge_exp(const int* __restrict__ ei,
                                                const int* __restrict__ ej,
                                                const float* __restrict__ s,
                                                const float* __restrict__ t,
                                                float* __restrict__ partial) {
    __shared__ float ls[4];
    const int e = blockIdx.x * 256 + threadIdx.x;   // 3125*256 = 800000 exact
    float v = __expf(lrelu(s[ei[e]] + t[ej[e]]));
#pragma unroll
    for (int off = 32; off > 0; off >>= 1)
        v += __shfl_down(v, off, 64);
    const int lane = threadIdx.x & 63, w = threadIdx.x >> 6;
    if (lane == 0) ls[w] = v;
    __syncthreads();
    if (threadIdx.x == 0)
        partial[blockIdx.x] = ls[0] + ls[1] + ls[2] + ls[3];
}

// single block: invZ = 1 / sum(partial)
__global__ __launch_bounds__(256) void reduce_Z(const float* __restrict__ partial,
                                                float* __restrict__ invZ) {
    __shared__ float ls[4];
    float v = 0.0f;
    for (int i = threadIdx.x; i < NBLK_E; i += 256) v += partial[i];
#pragma unroll
    for (int off = 32; off > 0; off >>= 1)
        v += __shfl_down(v, off, 64);
    const int lane = threadIdx.x & 63, w = threadIdx.x >> 6;
    if (lane == 0) ls[w] = v;
    __syncthreads();
    if (threadIdx.x == 0) *invZ = 1.0f / (ls[0] + ls[1] + ls[2] + ls[3]);
}

// per edge: out[ei][c] += alpha * h[ej][c]  (one wave per edge, 64 scalar
// fp32 HW atomics via unsafeAtomicAdd -> global_atomic_add_f32, no CAS)
__global__ __launch_bounds__(256) void scatter_msg(const int* __restrict__ ei,
                                                   const int* __restrict__ ej,
                                                   const float* __restrict__ s,
                                                   const float* __restrict__ t,
                                                   const float* __restrict__ invZ,
                                                   float* __restrict__ out) {
    const int e = blockIdx.x * 4 + (threadIdx.x >> 6);  // 200000*4 = 800000 exact
    const int lane = threadIdx.x & 63;
    const int li = ei[e];
    const int lj = ej[e];
    const float alpha = __expf(lrelu(s[li] + t[lj])) * invZ[0];
    const float hv = out[lj * ROW + 64 + lane];         // h lives in head-1 slots
    unsafeAtomicAdd(&out[li * ROW + lane], alpha * hv); // global_atomic_add_f32
}

// tile head-0 into heads 1..7 (overwrites the temporary h storage)
__global__ __launch_bounds__(256) void tile_heads(float* __restrict__ out) {
    float4* out4 = (float4*)out;
    const int n = blockIdx.x * 2 + (threadIdx.x >> 7);  // 25000*2 = 50000 exact
    const int j = threadIdx.x & 127;                    // float4 index in heads 1..7
    if (j < 112) {
        float4 v = out4[n * 128 + (j & 15)];            // read head-0
        out4[n * 128 + 16 + j] = v;                     // write heads 1..7
    }
}

extern "C" void kernel_launch(void* const* d_in, const int* in_sizes, int n_in,
                              void* d_out, int out_size, void* d_ws, size_t ws_size,
                              hipStream_t stream) {
    const float* x    = (const float*)d_in[0];
    const int*   eidx = (const int*)d_in[1];
    const float* W    = (const float*)d_in[2];
    const float* attn = (const float*)d_in[3];
    float* out = (float*)d_out;

    float* s = (float*)d_ws;                 // 50000
    float* t = s + N_NODES;                  // 50000
    float* partial = t + N_NODES;            // 3125
    float* invZ = partial + NBLK_E;          // 1    (~412 KB total ws)

    const int* ei = eidx;            // destinations
    const int* ej = eidx + N_EDGES;  // sources

    gemm_st    <<<N_NODES / 4, 256, 0, stream>>>(x, W, attn, out, s, t);
    edge_exp   <<<NBLK_E, 256, 0, stream>>>(ei, ej, s, t, partial);
    reduce_Z   <<<1, 256, 0, stream>>>(partial, invZ);
    scatter_msg<<<N_EDGES / 4, 256, 0, stream>>>(ei, ej, s, t, invZ, out);
    tile_heads <<<N_NODES / 2, 256, 0, stream>>>(out);
}

// Round 4
// 333.733 us; speedup vs baseline: 2.0113x; 1.1179x over previous
//
#include <hip/hip_runtime.h>

#define N_NODES 50000
#define N_EDGES 800000
#define IN_CH 128
#define OUT_CH 64
#define HEADS 8
#define ROW 512           // OUT_CH*HEADS, floats per output row
#define NBLK_E 3125       // N_EDGES / 256
#define NBLK_N 196        // ceil(N_NODES / 256)

__device__ __forceinline__ float lrelu(float z) {
    return z > 0.0f ? z : 0.2f * z;
}

// h = x @ W  -> stashed at out[n*ROW + 448 + c]  (head-7 slots, temporary)
// s[n] = h[n] . attn[0:64],  t[n] = h[n] . attn[64:128]
// first NBLK_N blocks also zero the degree-count array
__global__ __launch_bounds__(256) void gemm_st(const float* __restrict__ x,
                                               const float* __restrict__ W,
                                               const float* __restrict__ attn,
                                               float* __restrict__ out,
                                               float* __restrict__ s,
                                               float* __restrict__ t,
                                               int* __restrict__ count) {
    __shared__ float xs[4][IN_CH];
    const int w = threadIdx.x >> 6;
    const int lane = threadIdx.x & 63;
    const int row = blockIdx.x * 4 + w;           // 50000/4 = 12500 exact
    if (blockIdx.x < NBLK_N) {
        int idx = blockIdx.x * 256 + threadIdx.x;
        if (idx < N_NODES) count[idx] = 0;
    }
    // stage x row in LDS (wave-private; no barrier needed)
    xs[w][lane]      = x[row * IN_CH + lane];
    xs[w][lane + 64] = x[row * IN_CH + 64 + lane];
    float acc = 0.0f;
#pragma unroll 8
    for (int k = 0; k < IN_CH; ++k)
        acc = fmaf(xs[w][k], W[k * OUT_CH + lane], acc);
    out[row * ROW + 448 + lane] = acc;            // h lives in head-7 slots
    float sv = acc * attn[lane];
    float tv = acc * attn[64 + lane];
#pragma unroll
    for (int off = 32; off > 0; off >>= 1) {
        sv += __shfl_down(sv, off, 64);
        tv += __shfl_down(tv, off, 64);
    }
    if (lane == 0) { s[row] = sv; t[row] = tv; }
}

// per edge: degree histogram by destination + per-block partial of exp(logit)
// (no max subtraction: logits are small, exp safe in fp32; softmax shift-invariant)
__global__ __launch_bounds__(256) void count_exp(const int* __restrict__ ei,
                                                 const int* __restrict__ ej,
                                                 const float* __restrict__ s,
                                                 const float* __restrict__ t,
                                                 int* __restrict__ count,
                                                 float* __restrict__ partial) {
    __shared__ float ls[4];
    const int e = blockIdx.x * 256 + threadIdx.x;   // 3125*256 = 800000 exact
    const int li = ei[e];
    float v = __expf(lrelu(s[li] + t[ej[e]]));
    atomicAdd(&count[li], 1);
#pragma unroll
    for (int off = 32; off > 0; off >>= 1)
        v += __shfl_down(v, off, 64);
    const int lane = threadIdx.x & 63, w = threadIdx.x >> 6;
    if (lane == 0) ls[w] = v;
    __syncthreads();
    if (threadIdx.x == 0)
        partial[blockIdx.x] = ls[0] + ls[1] + ls[2] + ls[3];
}

// scan step 1: per-block exclusive scan of count -> rowptr (block-local), block sums
__global__ __launch_bounds__(256) void scan1(const int* __restrict__ count,
                                             int* __restrict__ rowptr,
                                             int* __restrict__ bsum) {
    __shared__ int ls[4];
    const int idx = blockIdx.x * 256 + threadIdx.x;
    const int lane = threadIdx.x & 63, w = threadIdx.x >> 6;
    const int c = (idx < N_NODES) ? count[idx] : 0;
    int v = c;
#pragma unroll
    for (int off = 1; off < 64; off <<= 1) {
        int u = __shfl_up(v, off, 64);
        if (lane >= off) v += u;
    }
    if (lane == 63) ls[w] = v;
    __syncthreads();
    int wo = 0;
    if (w > 0) wo = ls[0];
    if (w > 1) wo += ls[1];
    if (w > 2) wo += ls[2];
    if (idx < N_NODES) rowptr[idx] = wo + v - c;   // exclusive within block
    if (threadIdx.x == 255) bsum[blockIdx.x] = wo + v;
}

// scan step 2 (1 block): exclusive scan of bsum -> boff; also invZ from partials
__global__ __launch_bounds__(256) void scan2(const int* __restrict__ bsum,
                                             int* __restrict__ boff,
                                             const float* __restrict__ partial,
                                             float* __restrict__ invZ) {
    __shared__ int ls[4];
    __shared__ float fs[4];
    const int lane = threadIdx.x & 63, w = threadIdx.x >> 6;
    const int c = (threadIdx.x < NBLK_N) ? bsum[threadIdx.x] : 0;
    int v = c;
#pragma unroll
    for (int off = 1; off < 64; off <<= 1) {
        int u = __shfl_up(v, off, 64);
        if (lane >= off) v += u;
    }
    if (lane == 63) ls[w] = v;
    __syncthreads();
    int wo = 0;
    if (w > 0) wo = ls[0];
    if (w > 1) wo += ls[1];
    if (w > 2) wo += ls[2];
    if (threadIdx.x < NBLK_N) boff[threadIdx.x] = wo + v - c;

    float p = 0.0f;
    for (int i = threadIdx.x; i < NBLK_E; i += 256) p += partial[i];
#pragma unroll
    for (int off = 32; off > 0; off >>= 1)
        p += __shfl_down(p, off, 64);
    if (lane == 0) fs[w] = p;
    __syncthreads();
    if (threadIdx.x == 0) *invZ = 1.0f / (fs[0] + fs[1] + fs[2] + fs[3]);
}

// scan step 3: rowptr += block offset; init cursor; cap rowptr
__global__ __launch_bounds__(256) void scan3(int* __restrict__ rowptr,
                                             const int* __restrict__ boff,
                                             int* __restrict__ cursor) {
    const int idx = blockIdx.x * 256 + threadIdx.x;
    if (idx < N_NODES) {
        int r = rowptr[idx] + boff[blockIdx.x];
        rowptr[idx] = r;
        cursor[idx] = r;
    }
    if (idx == 0) rowptr[N_NODES] = N_EDGES;
}

// reorder edges into destination-sorted CSR column array
__global__ __launch_bounds__(256) void reorder(const int* __restrict__ ei,
                                               const int* __restrict__ ej,
                                               int* __restrict__ cursor,
                                               int* __restrict__ col) {
    const int e = blockIdx.x * 256 + threadIdx.x;
    const int li = ei[e];
    const int lj = ej[e];
    const int pos = atomicAdd(&cursor[li], 1);
    col[pos] = lj;
}

// one wave per destination node: acc = invZ * sum_e w_e * h[src_e]
// reads h from head-7 slots, writes heads 0..6 (no overlap -> no race)
__global__ __launch_bounds__(256) void gather_out(const int* __restrict__ rowptr,
                                                  const int* __restrict__ col,
                                                  const float* __restrict__ s,
                                                  const float* __restrict__ t,
                                                  const float* __restrict__ invZ,
                                                  float* __restrict__ out) {
    const int n = blockIdx.x * 4 + (threadIdx.x >> 6);  // 12500*4 = 50000 exact
    const int lane = threadIdx.x & 63;
    const int beg = rowptr[n];
    const int end = rowptr[n + 1];
    const float sn = s[n];
    float acc = 0.0f;
    int i = beg;
    for (; i + 1 < end; i += 2) {
        const int s0 = col[i];
        const int s1 = col[i + 1];
        const float w0 = __expf(lrelu(sn + t[s0]));
        const float w1 = __expf(lrelu(sn + t[s1]));
        const float h0 = out[s0 * ROW + 448 + lane];
        const float h1 = out[s1 * ROW + 448 + lane];
        acc = fmaf(w0, h0, acc);
        acc = fmaf(w1, h1, acc);
    }
    if (i < end) {
        const int s0 = col[i];
        const float w0 = __expf(lrelu(sn + t[s0]));
        acc = fmaf(w0, out[s0 * ROW + 448 + lane], acc);
    }
    acc *= invZ[0];
#pragma unroll
    for (int hh = 0; hh < 7; ++hh)
        out[n * ROW + hh * 64 + lane] = acc;
}

// final: head-7 slots (which held h) get the result from head-0
__global__ __launch_bounds__(256) void fix_head7(float* __restrict__ out) {
    const int tid = blockIdx.x * 256 + threadIdx.x;
    const int n = tid >> 6, c = tid & 63;
    out[n * ROW + 448 + c] = out[n * ROW + c];
}

extern "C" void kernel_launch(void* const* d_in, const int* in_sizes, int n_in,
                              void* d_out, int out_size, void* d_ws, size_t ws_size,
                              hipStream_t stream) {
    const float* x    = (const float*)d_in[0];
    const int*   eidx = (const int*)d_in[1];
    const float* W    = (const float*)d_in[2];
    const float* attn = (const float*)d_in[3];
    float* out = (float*)d_out;

    float* s       = (float*)d_ws;            // 50000
    float* t       = s + N_NODES;             // 50000
    float* partial = t + N_NODES;             // 3125
    float* invZ    = partial + NBLK_E;        // 1
    int*   count   = (int*)(invZ + 1);        // 50000
    int*   rowptr  = count + N_NODES;         // 50001
    int*   cursor  = rowptr + N_NODES + 1;    // 50000
    int*   bsum    = cursor + N_NODES;        // 256
    int*   boff    = bsum + 256;              // 256
    int*   col     = boff + 256;              // 800000   (total ~4.2 MB)

    const int* ei = eidx;            // destinations
    const int* ej = eidx + N_EDGES;  // sources

    gemm_st   <<<N_NODES / 4, 256, 0, stream>>>(x, W, attn, out, s, t, count);
    count_exp <<<NBLK_E, 256, 0, stream>>>(ei, ej, s, t, count, partial);
    scan1     <<<NBLK_N, 256, 0, stream>>>(count, rowptr, bsum);
    scan2     <<<1, 256, 0, stream>>>(bsum, boff, partial, invZ);
    scan3     <<<NBLK_N, 256, 0, stream>>>(rowptr, boff, cursor);
    reorder   <<<NBLK_E, 256, 0, stream>>>(ei, ej, cursor, col);
    gather_out<<<N_NODES / 4, 256, 0, stream>>>(rowptr, col, s, t, invZ, out);
    fix_head7 <<<(N_NODES * 64) / 256, 256, 0, stream>>>(out);
}

// Round 5
// 305.216 us; speedup vs baseline: 2.1992x; 1.0934x over previous
//
#include <hip/hip_runtime.h>

#define N_NODES 50000
#define N_EDGES 800000
#define IN_CH 128
#define OUT_CH 64
#define HEADS 8
#define ROW 512           // OUT_CH*HEADS, floats per output row
#define NBLK_E 3125       // N_EDGES / 256
#define NBLK_N 196        // ceil(N_NODES / 256)
#define GR 64             // gemm rows per block

__device__ __forceinline__ float lrelu(float z) {
    return z > 0.0f ? z : 0.2f * z;
}

// h = x @ W -> hbuf (compact [N,64]); s[n]=h.attn[0:64]; t[n]=h.attn[64:128]
// Register-tiled: W + 64-row x tile staged in LDS; 16 rows/wave in registers
// so each W element is read once per 16 rows (kills the 1.6 GB L1 W-traffic).
__global__ __launch_bounds__(256) void gemm_st(const float* __restrict__ x,
                                               const float* __restrict__ W,
                                               const float* __restrict__ attn,
                                               float* __restrict__ hbuf,
                                               float* __restrict__ s,
                                               float* __restrict__ t,
                                               int* __restrict__ count) {
    __shared__ float xs[GR][IN_CH];      // 32 KB
    __shared__ float wls[IN_CH][OUT_CH]; // 32 KB
    const int tid = threadIdx.x;
    if (blockIdx.x < NBLK_N) {
        int idx = blockIdx.x * 256 + tid;
        if (idx < N_NODES) count[idx] = 0;
    }
    const int base = blockIdx.x * GR;
    {   // stage W: 8192 floats = 2048 float4, coalesced
        const float4* W4 = (const float4*)W;
        float4* w4 = (float4*)wls;
#pragma unroll
        for (int i = 0; i < 8; ++i)
            w4[tid + i * 256] = W4[tid + i * 256];
    }
    {   // stage x tile: 2048 float4 (32 float4 per row), coalesced, guarded
        const float4* x4 = (const float4*)x;
        float4* xt4 = (float4*)xs;
#pragma unroll
        for (int i = 0; i < 8; ++i) {
            const int idx = tid + i * 256;
            const int row = base + (idx >> 5);
            float4 v = make_float4(0.f, 0.f, 0.f, 0.f);
            if (row < N_NODES) v = x4[(size_t)base * 32 + idx];
            xt4[idx] = v;
        }
    }
    __syncthreads();
    const int w = tid >> 6, lane = tid & 63;
    const int r0 = w * 16;               // wave handles rows r0..r0+15
    float acc[16];
#pragma unroll
    for (int r = 0; r < 16; ++r) acc[r] = 0.0f;
    for (int k4 = 0; k4 < IN_CH / 4; ++k4) {
        const float w0 = wls[4 * k4 + 0][lane];
        const float w1 = wls[4 * k4 + 1][lane];
        const float w2 = wls[4 * k4 + 2][lane];
        const float w3 = wls[4 * k4 + 3][lane];
#pragma unroll
        for (int r = 0; r < 16; ++r) {
            const float4 xv = *(const float4*)&xs[r0 + r][4 * k4];  // LDS bcast
            acc[r] = fmaf(xv.x, w0, acc[r]);
            acc[r] = fmaf(xv.y, w1, acc[r]);
            acc[r] = fmaf(xv.z, w2, acc[r]);
            acc[r] = fmaf(xv.w, w3, acc[r]);
        }
    }
    const float a1 = attn[lane], a2 = attn[64 + lane];
#pragma unroll
    for (int r = 0; r < 16; ++r) {
        const int row = base + r0 + r;
        const bool ok = row < N_NODES;
        if (ok) hbuf[row * OUT_CH + lane] = acc[r];
        float sv = acc[r] * a1, tv = acc[r] * a2;
#pragma unroll
        for (int off = 32; off > 0; off >>= 1) {
            sv += __shfl_down(sv, off, 64);
            tv += __shfl_down(tv, off, 64);
        }
        if (lane == 0 && ok) { s[row] = sv; t[row] = tv; }
    }
}

// per edge: degree histogram by destination + per-block partial of exp(logit)
// (no max subtraction: logits are small, exp safe in fp32; softmax shift-invariant)
__global__ __launch_bounds__(256) void count_exp(const int* __restrict__ ei,
                                                 const int* __restrict__ ej,
                                                 const float* __restrict__ s,
                                                 const float* __restrict__ t,
                                                 int* __restrict__ count,
                                                 float* __restrict__ partial) {
    __shared__ float ls[4];
    const int e = blockIdx.x * 256 + threadIdx.x;   // 3125*256 = 800000 exact
    const int li = ei[e];
    float v = __expf(lrelu(s[li] + t[ej[e]]));
    atomicAdd(&count[li], 1);
#pragma unroll
    for (int off = 32; off > 0; off >>= 1)
        v += __shfl_down(v, off, 64);
    const int lane = threadIdx.x & 63, w = threadIdx.x >> 6;
    if (lane == 0) ls[w] = v;
    __syncthreads();
    if (threadIdx.x == 0)
        partial[blockIdx.x] = ls[0] + ls[1] + ls[2] + ls[3];
}

// scan step 1: per-block exclusive scan of count -> rowptr (block-local), block sums
__global__ __launch_bounds__(256) void scan1(const int* __restrict__ count,
                                             int* __restrict__ rowptr,
                                             int* __restrict__ bsum) {
    __shared__ int ls[4];
    const int idx = blockIdx.x * 256 + threadIdx.x;
    const int lane = threadIdx.x & 63, w = threadIdx.x >> 6;
    const int c = (idx < N_NODES) ? count[idx] : 0;
    int v = c;
#pragma unroll
    for (int off = 1; off < 64; off <<= 1) {
        int u = __shfl_up(v, off, 64);
        if (lane >= off) v += u;
    }
    if (lane == 63) ls[w] = v;
    __syncthreads();
    int wo = 0;
    if (w > 0) wo = ls[0];
    if (w > 1) wo += ls[1];
    if (w > 2) wo += ls[2];
    if (idx < N_NODES) rowptr[idx] = wo + v - c;   // exclusive within block
    if (threadIdx.x == 255) bsum[blockIdx.x] = wo + v;
}

// scan step 2 (1 block): exclusive scan of bsum -> boff; also invZ from partials
__global__ __launch_bounds__(256) void scan2(const int* __restrict__ bsum,
                                             int* __restrict__ boff,
                                             const float* __restrict__ partial,
                                             float* __restrict__ invZ) {
    __shared__ int ls[4];
    __shared__ float fs[4];
    const int lane = threadIdx.x & 63, w = threadIdx.x >> 6;
    const int c = (threadIdx.x < NBLK_N) ? bsum[threadIdx.x] : 0;
    int v = c;
#pragma unroll
    for (int off = 1; off < 64; off <<= 1) {
        int u = __shfl_up(v, off, 64);
        if (lane >= off) v += u;
    }
    if (lane == 63) ls[w] = v;
    __syncthreads();
    int wo = 0;
    if (w > 0) wo = ls[0];
    if (w > 1) wo += ls[1];
    if (w > 2) wo += ls[2];
    if (threadIdx.x < NBLK_N) boff[threadIdx.x] = wo + v - c;

    float p = 0.0f;
    for (int i = threadIdx.x; i < NBLK_E; i += 256) p += partial[i];
#pragma unroll
    for (int off = 32; off > 0; off >>= 1)
        p += __shfl_down(p, off, 64);
    if (lane == 0) fs[w] = p;
    __syncthreads();
    if (threadIdx.x == 0) *invZ = 1.0f / (fs[0] + fs[1] + fs[2] + fs[3]);
}

// scan step 3: rowptr += block offset; init cursor; cap rowptr
__global__ __launch_bounds__(256) void scan3(int* __restrict__ rowptr,
                                             const int* __restrict__ boff,
                                             int* __restrict__ cursor) {
    const int idx = blockIdx.x * 256 + threadIdx.x;
    if (idx < N_NODES) {
        int r = rowptr[idx] + boff[blockIdx.x];
        rowptr[idx] = r;
        cursor[idx] = r;
    }
    if (idx == 0) rowptr[N_NODES] = N_EDGES;
}

// reorder edges into destination-sorted CSR column array
__global__ __launch_bounds__(256) void reorder(const int* __restrict__ ei,
                                               const int* __restrict__ ej,
                                               int* __restrict__ cursor,
                                               int* __restrict__ col) {
    const int e = blockIdx.x * 256 + threadIdx.x;
    const int li = ei[e];
    const int lj = ej[e];
    const int pos = atomicAdd(&cursor[li], 1);
    col[pos] = lj;
}

// one wave per destination node: acc = invZ * sum_e w_e * h[src_e]
// h from compact hbuf (12.8 MB, cache-resident); writes all 8 heads fused.
__global__ __launch_bounds__(256) void gather_out(const int* __restrict__ rowptr,
                                                  const int* __restrict__ col,
                                                  const float* __restrict__ s,
                                                  const float* __restrict__ t,
                                                  const float* __restrict__ invZ,
                                                  const float* __restrict__ hbuf,
                                                  float* __restrict__ out) {
    const int n = blockIdx.x * 4 + (threadIdx.x >> 6);  // 12500*4 = 50000 exact
    const int lane = threadIdx.x & 63;
    const int beg = rowptr[n];
    const int end = rowptr[n + 1];
    const float sn = s[n];
    float acc = 0.0f;
    int i = beg;
    for (; i + 3 < end; i += 4) {
        const int s0 = col[i], s1 = col[i + 1], s2 = col[i + 2], s3 = col[i + 3];
        const float w0 = __expf(lrelu(sn + t[s0]));
        const float w1 = __expf(lrelu(sn + t[s1]));
        const float w2 = __expf(lrelu(sn + t[s2]));
        const float w3 = __expf(lrelu(sn + t[s3]));
        const float h0 = hbuf[s0 * OUT_CH + lane];
        const float h1 = hbuf[s1 * OUT_CH + lane];
        const float h2 = hbuf[s2 * OUT_CH + lane];
        const float h3 = hbuf[s3 * OUT_CH + lane];
        acc = fmaf(w0, h0, acc);
        acc = fmaf(w1, h1, acc);
        acc = fmaf(w2, h2, acc);
        acc = fmaf(w3, h3, acc);
    }
    for (; i < end; ++i) {
        const int s0 = col[i];
        acc = fmaf(__expf(lrelu(sn + t[s0])), hbuf[s0 * OUT_CH + lane], acc);
    }
    acc *= invZ[0];
#pragma unroll
    for (int hh = 0; hh < HEADS; ++hh)
        out[n * ROW + hh * 64 + lane] = acc;
}

extern "C" void kernel_launch(void* const* d_in, const int* in_sizes, int n_in,
                              void* d_out, int out_size, void* d_ws, size_t ws_size,
                              hipStream_t stream) {
    const float* x    = (const float*)d_in[0];
    const int*   eidx = (const int*)d_in[1];
    const float* W    = (const float*)d_in[2];
    const float* attn = (const float*)d_in[3];
    float* out = (float*)d_out;

    float* s       = (float*)d_ws;            // 50000
    float* t       = s + N_NODES;             // 50000
    float* partial = t + N_NODES;             // 3125
    float* invZ    = partial + NBLK_E;        // 1
    int*   count   = (int*)(invZ + 1);        // 50000
    int*   rowptr  = count + N_NODES;         // 50001
    int*   cursor  = rowptr + N_NODES + 1;    // 50000
    int*   bsum    = cursor + N_NODES;        // 256
    int*   boff    = bsum + 256;              // 256
    int*   col     = boff + 256;              // 800000
    float* hbuf    = (float*)(col + N_EDGES); // 3200000  (total ~17 MB)

    const int* ei = eidx;            // destinations
    const int* ej = eidx + N_EDGES;  // sources

    gemm_st   <<<(N_NODES + GR - 1) / GR, 256, 0, stream>>>(x, W, attn, hbuf, s, t, count);
    count_exp <<<NBLK_E, 256, 0, stream>>>(ei, ej, s, t, count, partial);
    scan1     <<<NBLK_N, 256, 0, stream>>>(count, rowptr, bsum);
    scan2     <<<1, 256, 0, stream>>>(bsum, boff, partial, invZ);
    scan3     <<<NBLK_N, 256, 0, stream>>>(rowptr, boff, cursor);
    reorder   <<<NBLK_E, 256, 0, stream>>>(ei, ej, cursor, col);
    gather_out<<<N_NODES / 4, 256, 0, stream>>>(rowptr, col, s, t, invZ, hbuf, out);
}

// Round 6
// 257.132 us; speedup vs baseline: 2.6105x; 1.1870x over previous
//
#include <hip/hip_runtime.h>

#define N_NODES 50000
#define N_EDGES 800000
#define IN_CH 128
#define OUT_CH 64
#define HEADS 8
#define ROW 512           // OUT_CH*HEADS, floats per output row
#define NBLK_E 3125       // N_EDGES / 256
#define NBLK_N 196        // ceil(N_NODES / 256)
#define GR 64             // gemm rows per block

__device__ __forceinline__ float lrelu(float z) {
    return z > 0.0f ? z : 0.2f * z;
}

// h = x @ W -> hbuf (compact [N,64]); s[n]=h.attn[0:64]; t[n]=h.attn[64:128]
// Register-tiled: W + 64-row x tile staged in LDS; 16 rows/wave in registers.
__global__ __launch_bounds__(256) void gemm_st(const float* __restrict__ x,
                                               const float* __restrict__ W,
                                               const float* __restrict__ attn,
                                               float* __restrict__ hbuf,
                                               float* __restrict__ s,
                                               float* __restrict__ t,
                                               int* __restrict__ count) {
    __shared__ float xs[GR][IN_CH];      // 32 KB
    __shared__ float wls[IN_CH][OUT_CH]; // 32 KB
    const int tid = threadIdx.x;
    if (blockIdx.x < NBLK_N) {
        int idx = blockIdx.x * 256 + tid;
        if (idx < N_NODES) count[idx] = 0;
    }
    const int base = blockIdx.x * GR;
    {   // stage W: 8192 floats = 2048 float4, coalesced
        const float4* W4 = (const float4*)W;
        float4* w4 = (float4*)wls;
#pragma unroll
        for (int i = 0; i < 8; ++i)
            w4[tid + i * 256] = W4[tid + i * 256];
    }
    {   // stage x tile: 2048 float4 (32 float4 per row), coalesced, guarded
        const float4* x4 = (const float4*)x;
        float4* xt4 = (float4*)xs;
#pragma unroll
        for (int i = 0; i < 8; ++i) {
            const int idx = tid + i * 256;
            const int row = base + (idx >> 5);
            float4 v = make_float4(0.f, 0.f, 0.f, 0.f);
            if (row < N_NODES) v = x4[(size_t)base * 32 + idx];
            xt4[idx] = v;
        }
    }
    __syncthreads();
    const int w = tid >> 6, lane = tid & 63;
    const int r0 = w * 16;               // wave handles rows r0..r0+15
    float acc[16];
#pragma unroll
    for (int r = 0; r < 16; ++r) acc[r] = 0.0f;
    for (int k4 = 0; k4 < IN_CH / 4; ++k4) {
        const float w0 = wls[4 * k4 + 0][lane];
        const float w1 = wls[4 * k4 + 1][lane];
        const float w2 = wls[4 * k4 + 2][lane];
        const float w3 = wls[4 * k4 + 3][lane];
#pragma unroll
        for (int r = 0; r < 16; ++r) {
            const float4 xv = *(const float4*)&xs[r0 + r][4 * k4];  // LDS bcast
            acc[r] = fmaf(xv.x, w0, acc[r]);
            acc[r] = fmaf(xv.y, w1, acc[r]);
            acc[r] = fmaf(xv.z, w2, acc[r]);
            acc[r] = fmaf(xv.w, w3, acc[r]);
        }
    }
    const float a1 = attn[lane], a2 = attn[64 + lane];
#pragma unroll
    for (int r = 0; r < 16; ++r) {
        const int row = base + r0 + r;
        const bool ok = row < N_NODES;
        if (ok) hbuf[row * OUT_CH + lane] = acc[r];
        float sv = acc[r] * a1, tv = acc[r] * a2;
#pragma unroll
        for (int off = 32; off > 0; off >>= 1) {
            sv += __shfl_down(sv, off, 64);
            tv += __shfl_down(tv, off, 64);
        }
        if (lane == 0 && ok) { s[row] = sv; t[row] = tv; }
    }
}

// per edge: degree histogram by destination (saving each edge's rank = atomic
// return), per-edge weight wexp[e] = exp(leaky_relu(logit)), and per-block
// partial sums for the global softmax denominator.
__global__ __launch_bounds__(256) void count_exp(const int* __restrict__ ei,
                                                 const int* __restrict__ ej,
                                                 const float* __restrict__ s,
                                                 const float* __restrict__ t,
                                                 int* __restrict__ count,
                                                 float* __restrict__ partial,
                                                 int* __restrict__ rank,
                                                 float* __restrict__ wexp) {
    __shared__ float ls[4];
    const int e = blockIdx.x * 256 + threadIdx.x;   // 3125*256 = 800000 exact
    const int li = ei[e];
    float v = __expf(lrelu(s[li] + t[ej[e]]));
    wexp[e] = v;
    rank[e] = atomicAdd(&count[li], 1);
#pragma unroll
    for (int off = 32; off > 0; off >>= 1)
        v += __shfl_down(v, off, 64);
    const int lane = threadIdx.x & 63, w = threadIdx.x >> 6;
    if (lane == 0) ls[w] = v;
    __syncthreads();
    if (threadIdx.x == 0)
        partial[blockIdx.x] = ls[0] + ls[1] + ls[2] + ls[3];
}

// scan step 1: per-block exclusive scan of count -> rowptr (block-local), block sums
__global__ __launch_bounds__(256) void scan1(const int* __restrict__ count,
                                             int* __restrict__ rowptr,
                                             int* __restrict__ bsum) {
    __shared__ int ls[4];
    const int idx = blockIdx.x * 256 + threadIdx.x;
    const int lane = threadIdx.x & 63, w = threadIdx.x >> 6;
    const int c = (idx < N_NODES) ? count[idx] : 0;
    int v = c;
#pragma unroll
    for (int off = 1; off < 64; off <<= 1) {
        int u = __shfl_up(v, off, 64);
        if (lane >= off) v += u;
    }
    if (lane == 63) ls[w] = v;
    __syncthreads();
    int wo = 0;
    if (w > 0) wo = ls[0];
    if (w > 1) wo += ls[1];
    if (w > 2) wo += ls[2];
    if (idx < N_NODES) rowptr[idx] = wo + v - c;   // exclusive within block
    if (threadIdx.x == 255) bsum[blockIdx.x] = wo + v;
}

// scan step 2 (1 block): exclusive scan of bsum -> boff; also invZ from partials
__global__ __launch_bounds__(256) void scan2(const int* __restrict__ bsum,
                                             int* __restrict__ boff,
                                             const float* __restrict__ partial,
                                             float* __restrict__ invZ) {
    __shared__ int ls[4];
    __shared__ float fs[4];
    const int lane = threadIdx.x & 63, w = threadIdx.x >> 6;
    const int c = (threadIdx.x < NBLK_N) ? bsum[threadIdx.x] : 0;
    int v = c;
#pragma unroll
    for (int off = 1; off < 64; off <<= 1) {
        int u = __shfl_up(v, off, 64);
        if (lane >= off) v += u;
    }
    if (lane == 63) ls[w] = v;
    __syncthreads();
    int wo = 0;
    if (w > 0) wo = ls[0];
    if (w > 1) wo += ls[1];
    if (w > 2) wo += ls[2];
    if (threadIdx.x < NBLK_N) boff[threadIdx.x] = wo + v - c;

    float p = 0.0f;
    for (int i = threadIdx.x; i < NBLK_E; i += 256) p += partial[i];
#pragma unroll
    for (int off = 32; off > 0; off >>= 1)
        p += __shfl_down(p, off, 64);
    if (lane == 0) fs[w] = p;
    __syncthreads();
    if (threadIdx.x == 0) *invZ = 1.0f / (fs[0] + fs[1] + fs[2] + fs[3]);
}

// scan step 3: rowptr += block offset; cap rowptr
__global__ __launch_bounds__(256) void scan3(int* __restrict__ rowptr,
                                             const int* __restrict__ boff) {
    const int idx = blockIdx.x * 256 + threadIdx.x;
    if (idx < N_NODES) rowptr[idx] += boff[blockIdx.x];
    if (idx == 0) rowptr[N_NODES] = N_EDGES;
}

// reorder edges into destination-sorted CSR, packing (src, weight) as int2.
// pos = rowptr[li] + rank[e] -> NO atomics here.
__global__ __launch_bounds__(256) void reorder(const int* __restrict__ ei,
                                               const int* __restrict__ ej,
                                               const int* __restrict__ rank,
                                               const float* __restrict__ wexp,
                                               const int* __restrict__ rowptr,
                                               int2* __restrict__ cv) {
    const int e = blockIdx.x * 256 + threadIdx.x;
    const int li = ei[e];
    const int pos = rowptr[li] + rank[e];
    cv[pos] = make_int2(ej[e], __float_as_int(wexp[e]));
}

// one wave per destination node. Lane layout: sub = lane>>4 (edge slot 0..3),
// q = lane&15 (float4 quarter of the 64-float h row). One float4 h-load
// serves 4 edges -> 4x fewer VMEM insts than scalar; weight arrives packed
// with col (no dependent t-gather / exp recompute). xor-shuffle reduce, then
// two coalesced 1KB stores cover all 8 heads.
__global__ __launch_bounds__(256) void gather_out(const int* __restrict__ rowptr,
                                                  const int2* __restrict__ cv,
                                                  const float* __restrict__ invZ,
                                                  const float* __restrict__ hbuf,
                                                  float* __restrict__ out) {
    const int n = blockIdx.x * 4 + (threadIdx.x >> 6);  // 12500*4 = 50000 exact
    const int lane = threadIdx.x & 63;
    const int sub = lane >> 4;
    const int q = lane & 15;
    const int beg = rowptr[n];
    const int end = rowptr[n + 1];
    const float4* h4 = (const float4*)hbuf;
    float4 acc = make_float4(0.f, 0.f, 0.f, 0.f);
    for (int i = beg; i < end; i += 4) {
        const int ee = i + sub;
        int c = 0;
        float w = 0.0f;
        if (ee < end) {
            const int2 p = cv[ee];
            c = p.x;
            w = __int_as_float(p.y);
        }
        const float4 hv = h4[c * 16 + q];
        acc.x = fmaf(w, hv.x, acc.x);
        acc.y = fmaf(w, hv.y, acc.y);
        acc.z = fmaf(w, hv.z, acc.z);
        acc.w = fmaf(w, hv.w, acc.w);
    }
#pragma unroll
    for (int off = 16; off <= 32; off <<= 1) {
        acc.x += __shfl_xor(acc.x, off, 64);
        acc.y += __shfl_xor(acc.y, off, 64);
        acc.z += __shfl_xor(acc.z, off, 64);
        acc.w += __shfl_xor(acc.w, off, 64);
    }
    const float iz = invZ[0];
    acc.x *= iz; acc.y *= iz; acc.z *= iz; acc.w *= iz;
    float4* out4 = (float4*)out;
    const int base = n * 128;                 // 128 float4 per output row
    out4[base + lane] = acc;                  // heads 0..3 (sub*16+q == lane)
    out4[base + 64 + lane] = acc;             // heads 4..7
}

extern "C" void kernel_launch(void* const* d_in, const int* in_sizes, int n_in,
                              void* d_out, int out_size, void* d_ws, size_t ws_size,
                              hipStream_t stream) {
    const float* x    = (const float*)d_in[0];
    const int*   eidx = (const int*)d_in[1];
    const float* W    = (const float*)d_in[2];
    const float* attn = (const float*)d_in[3];
    float* out = (float*)d_out;

    float* hbuf    = (float*)d_ws;                      // 3,200,000 f (16B-aligned base)
    int2*  cv      = (int2*)(hbuf + N_NODES * OUT_CH);  // 800,000 int2 (8B-aligned)
    int*   rank    = (int*)(cv + N_EDGES);              // 800,000
    float* wexp    = (float*)(rank + N_EDGES);          // 800,000
    float* s       = wexp + N_EDGES;                    // 50,000
    float* t       = s + N_NODES;                       // 50,000
    float* partial = t + N_NODES;                       // 3,125
    float* invZ    = partial + NBLK_E;                  // 1
    int*   count   = (int*)(invZ + 1);                  // 50,000
    int*   rowptr  = count + N_NODES;                   // 50,001
    int*   bsum    = rowptr + N_NODES + 1;              // 256
    int*   boff    = bsum + 256;                        // 256   (~27 MB total)

    const int* ei = eidx;            // destinations
    const int* ej = eidx + N_EDGES;  // sources

    gemm_st   <<<(N_NODES + GR - 1) / GR, 256, 0, stream>>>(x, W, attn, hbuf, s, t, count);
    count_exp <<<NBLK_E, 256, 0, stream>>>(ei, ej, s, t, count, partial, rank, wexp);
    scan1     <<<NBLK_N, 256, 0, stream>>>(count, rowptr, bsum);
    scan2     <<<1, 256, 0, stream>>>(bsum, boff, partial, invZ);
    scan3     <<<NBLK_N, 256, 0, stream>>>(rowptr, boff);
    reorder   <<<NBLK_E, 256, 0, stream>>>(ei, ej, rank, wexp, rowptr, cv);
    gather_out<<<N_NODES / 4, 256, 0, stream>>>(rowptr, cv, invZ, hbuf, out);
}

// Round 7
// 244.290 us; speedup vs baseline: 2.7477x; 1.0526x over previous
//
#include <hip/hip_runtime.h>
#include <hip/hip_bf16.h>

#define N_NODES 50000
#define N_EDGES 800000
#define IN_CH 128
#define OUT_CH 64
#define HEADS 8
#define ROW 512           // OUT_CH*HEADS, floats per output row
#define NBLK_E 3125       // N_EDGES / 256
#define NBLK_N 196        // ceil(N_NODES / 256)
#define GR 64             // gemm rows per block

__device__ __forceinline__ float lrelu(float z) {
    return z > 0.0f ? z : 0.2f * z;
}

// fp32 -> bf16 (RNE) as raw ushort
__device__ __forceinline__ unsigned short f2b(float f) {
    unsigned u = __float_as_uint(f);
    u = (u + 0x7FFFu + ((u >> 16) & 1u)) >> 16;
    return (unsigned short)u;
}

// h = x @ W -> hbuf (bf16 [N,64]); s[n]=h.attn[0:64]; t[n]=h.attn[64:128] (fp32)
__global__ __launch_bounds__(256) void gemm_st(const float* __restrict__ x,
                                               const float* __restrict__ W,
                                               const float* __restrict__ attn,
                                               unsigned short* __restrict__ hbuf,
                                               float* __restrict__ s,
                                               float* __restrict__ t,
                                               int* __restrict__ count) {
    __shared__ float xs[GR][IN_CH];      // 32 KB
    __shared__ float wls[IN_CH][OUT_CH]; // 32 KB
    const int tid = threadIdx.x;
    if (blockIdx.x < NBLK_N) {
        int idx = blockIdx.x * 256 + tid;
        if (idx < N_NODES) count[idx] = 0;
    }
    const int base = blockIdx.x * GR;
    {   // stage W: 8192 floats = 2048 float4, coalesced
        const float4* W4 = (const float4*)W;
        float4* w4 = (float4*)wls;
#pragma unroll
        for (int i = 0; i < 8; ++i)
            w4[tid + i * 256] = W4[tid + i * 256];
    }
    {   // stage x tile: 2048 float4, coalesced, guarded
        const float4* x4 = (const float4*)x;
        float4* xt4 = (float4*)xs;
#pragma unroll
        for (int i = 0; i < 8; ++i) {
            const int idx = tid + i * 256;
            const int row = base + (idx >> 5);
            float4 v = make_float4(0.f, 0.f, 0.f, 0.f);
            if (row < N_NODES) v = x4[(size_t)base * 32 + idx];
            xt4[idx] = v;
        }
    }
    __syncthreads();
    const int w = tid >> 6, lane = tid & 63;
    const int r0 = w * 16;               // wave handles rows r0..r0+15
    float acc[16];
#pragma unroll
    for (int r = 0; r < 16; ++r) acc[r] = 0.0f;
    for (int k4 = 0; k4 < IN_CH / 4; ++k4) {
        const float w0 = wls[4 * k4 + 0][lane];
        const float w1 = wls[4 * k4 + 1][lane];
        const float w2 = wls[4 * k4 + 2][lane];
        const float w3 = wls[4 * k4 + 3][lane];
#pragma unroll
        for (int r = 0; r < 16; ++r) {
            const float4 xv = *(const float4*)&xs[r0 + r][4 * k4];  // LDS bcast
            acc[r] = fmaf(xv.x, w0, acc[r]);
            acc[r] = fmaf(xv.y, w1, acc[r]);
            acc[r] = fmaf(xv.z, w2, acc[r]);
            acc[r] = fmaf(xv.w, w3, acc[r]);
        }
    }
    const float a1 = attn[lane], a2 = attn[64 + lane];
#pragma unroll
    for (int r = 0; r < 16; ++r) {
        const int row = base + r0 + r;
        const bool ok = row < N_NODES;
        if (ok) hbuf[row * OUT_CH + lane] = f2b(acc[r]);
        float sv = acc[r] * a1, tv = acc[r] * a2;
#pragma unroll
        for (int off = 32; off > 0; off >>= 1) {
            sv += __shfl_down(sv, off, 64);
            tv += __shfl_down(tv, off, 64);
        }
        if (lane == 0 && ok) { s[row] = sv; t[row] = tv; }
    }
}

// per edge: degree histogram (rank = atomic return), weight wexp[e], per-block
// partial sums of exp for the global softmax denominator
__global__ __launch_bounds__(256) void count_exp(const int* __restrict__ ei,
                                                 const int* __restrict__ ej,
                                                 const float* __restrict__ s,
                                                 const float* __restrict__ t,
                                                 int* __restrict__ count,
                                                 float* __restrict__ partial,
                                                 int* __restrict__ rank,
                                                 float* __restrict__ wexp) {
    __shared__ float ls[4];
    const int e = blockIdx.x * 256 + threadIdx.x;   // 3125*256 = 800000 exact
    const int li = ei[e];
    float v = __expf(lrelu(s[li] + t[ej[e]]));
    wexp[e] = v;
    rank[e] = atomicAdd(&count[li], 1);
#pragma unroll
    for (int off = 32; off > 0; off >>= 1)
        v += __shfl_down(v, off, 64);
    const int lane = threadIdx.x & 63, w = threadIdx.x >> 6;
    if (lane == 0) ls[w] = v;
    __syncthreads();
    if (threadIdx.x == 0)
        partial[blockIdx.x] = ls[0] + ls[1] + ls[2] + ls[3];
}

// scanA: blocks 0..195 = per-block exclusive scan of count -> rowptrL + bsum;
//        block 196 = reduce partial[] -> zsum
__global__ __launch_bounds__(256) void scanA(const int* __restrict__ count,
                                             int* __restrict__ rowptrL,
                                             int* __restrict__ bsum,
                                             const float* __restrict__ partial,
                                             float* __restrict__ zsum) {
    const int lane = threadIdx.x & 63, w = threadIdx.x >> 6;
    if (blockIdx.x == NBLK_N) {
        __shared__ float fs[4];
        float p = 0.0f;
        for (int i = threadIdx.x; i < NBLK_E; i += 256) p += partial[i];
#pragma unroll
        for (int off = 32; off > 0; off >>= 1)
            p += __shfl_down(p, off, 64);
        if (lane == 0) fs[w] = p;
        __syncthreads();
        if (threadIdx.x == 0) *zsum = fs[0] + fs[1] + fs[2] + fs[3];
        return;
    }
    __shared__ int ls[4];
    const int idx = blockIdx.x * 256 + threadIdx.x;
    const int c = (idx < N_NODES) ? count[idx] : 0;
    int v = c;
#pragma unroll
    for (int off = 1; off < 64; off <<= 1) {
        int u = __shfl_up(v, off, 64);
        if (lane >= off) v += u;
    }
    if (lane == 63) ls[w] = v;
    __syncthreads();
    int wo = 0;
    if (w > 0) wo = ls[0];
    if (w > 1) wo += ls[1];
    if (w > 2) wo += ls[2];
    if (idx < N_NODES) rowptrL[idx] = wo + v - c;   // exclusive within block
    if (threadIdx.x == 255) bsum[blockIdx.x] = wo + v;
}

// scanB (1 block): exclusive scan bsum -> boff; invZ = 1/zsum;
// rowptrL[N_NODES] set so that end-of-last-node resolves to N_EDGES
__global__ __launch_bounds__(256) void scanB(const int* __restrict__ bsum,
                                             int* __restrict__ boff,
                                             const float* __restrict__ zsum,
                                             float* __restrict__ invZ,
                                             int* __restrict__ rowptrL) {
    __shared__ int ls[4];
    const int lane = threadIdx.x & 63, w = threadIdx.x >> 6;
    const int c = (threadIdx.x < NBLK_N) ? bsum[threadIdx.x] : 0;
    int v = c;
#pragma unroll
    for (int off = 1; off < 64; off <<= 1) {
        int u = __shfl_up(v, off, 64);
        if (lane >= off) v += u;
    }
    if (lane == 63) ls[w] = v;
    __syncthreads();
    int wo = 0;
    if (w > 0) wo = ls[0];
    if (w > 1) wo += ls[1];
    if (w > 2) wo += ls[2];
    const int excl = wo + v - c;
    if (threadIdx.x < NBLK_N) boff[threadIdx.x] = excl;
    // rowptrL[50000] + boff[50000>>8] == N_EDGES  (50000>>8 == 195)
    if (threadIdx.x == NBLK_N - 1) rowptrL[N_NODES] = N_EDGES - excl;
    if (threadIdx.x == 0) *invZ = 1.0f / zsum[0];
}

// reorder into destination-sorted CSR, packing (src, weight) as int2. No atomics.
__global__ __launch_bounds__(256) void reorder(const int* __restrict__ ei,
                                               const int* __restrict__ ej,
                                               const int* __restrict__ rank,
                                               const float* __restrict__ wexp,
                                               const int* __restrict__ rowptrL,
                                               const int* __restrict__ boff,
                                               int2* __restrict__ cv) {
    const int e = blockIdx.x * 256 + threadIdx.x;
    const int li = ei[e];
    const int pos = rowptrL[li] + boff[li >> 8] + rank[e];
    cv[pos] = make_int2(ej[e], __float_as_int(wexp[e]));
}

// one wave per destination node; sub = lane>>4 (edge slot), q = lane&15
// (8-byte chunk of the 128-byte bf16 h row). One uint2 load = 4 h values,
// serving 4 edges per wave-instr; weight packed with col; xor-shuffle reduce;
// two coalesced 1KB stores for all 8 heads.
__global__ __launch_bounds__(256) void gather_out(const int* __restrict__ rowptrL,
                                                  const int* __restrict__ boff,
                                                  const int2* __restrict__ cv,
                                                  const float* __restrict__ invZ,
                                                  const unsigned short* __restrict__ hbuf,
                                                  float* __restrict__ out) {
    const int n = blockIdx.x * 4 + (threadIdx.x >> 6);  // 12500*4 = 50000 exact
    const int lane = threadIdx.x & 63;
    const int sub = lane >> 4;
    const int q = lane & 15;
    const int beg = rowptrL[n] + boff[n >> 8];
    const int end = rowptrL[n + 1] + boff[(n + 1) >> 8];
    const uint2* h2 = (const uint2*)hbuf;
    float4 acc = make_float4(0.f, 0.f, 0.f, 0.f);
    for (int i = beg; i < end; i += 4) {
        const int ee = i + sub;
        int c = 0;
        float w = 0.0f;
        if (ee < end) {
            const int2 p = cv[ee];
            c = p.x;
            w = __int_as_float(p.y);
        }
        const uint2 hv = h2[c * 16 + q];          // 4 bf16 h values
        const float h0 = __uint_as_float(hv.x << 16);
        const float h1 = __uint_as_float(hv.x & 0xFFFF0000u);
        const float h2f = __uint_as_float(hv.y << 16);
        const float h3 = __uint_as_float(hv.y & 0xFFFF0000u);
        acc.x = fmaf(w, h0, acc.x);
        acc.y = fmaf(w, h1, acc.y);
        acc.z = fmaf(w, h2f, acc.z);
        acc.w = fmaf(w, h3, acc.w);
    }
#pragma unroll
    for (int off = 16; off <= 32; off <<= 1) {
        acc.x += __shfl_xor(acc.x, off, 64);
        acc.y += __shfl_xor(acc.y, off, 64);
        acc.z += __shfl_xor(acc.z, off, 64);
        acc.w += __shfl_xor(acc.w, off, 64);
    }
    const float iz = invZ[0];
    acc.x *= iz; acc.y *= iz; acc.z *= iz; acc.w *= iz;
    float4* out4 = (float4*)out;
    const int base = n * 128;                 // 128 float4 per output row
    out4[base + lane] = acc;                  // heads 0..3 (sub*16+q == lane)
    out4[base + 64 + lane] = acc;             // heads 4..7
}

extern "C" void kernel_launch(void* const* d_in, const int* in_sizes, int n_in,
                              void* d_out, int out_size, void* d_ws, size_t ws_size,
                              hipStream_t stream) {
    const float* x    = (const float*)d_in[0];
    const int*   eidx = (const int*)d_in[1];
    const float* W    = (const float*)d_in[2];
    const float* attn = (const float*)d_in[3];
    float* out = (float*)d_out;

    unsigned short* hbuf = (unsigned short*)d_ws;       // 3,200,000 bf16 (6.4 MB)
    int2*  cv      = (int2*)(hbuf + N_NODES * OUT_CH);  // 800,000 int2
    int*   rank    = (int*)(cv + N_EDGES);              // 800,000
    float* wexp    = (float*)(rank + N_EDGES);          // 800,000
    float* s       = wexp + N_EDGES;                    // 50,000
    float* t       = s + N_NODES;                       // 50,000
    float* partial = t + N_NODES;                       // 3,125
    float* zsum    = partial + NBLK_E;                  // 1
    float* invZ    = zsum + 1;                          // 1
    int*   count   = (int*)(invZ + 1);                  // 50,000
    int*   rowptrL = count + N_NODES;                   // 50,001
    int*   bsum    = rowptrL + N_NODES + 1;             // 256
    int*   boff    = bsum + 256;                        // 256   (~21 MB total)

    const int* ei = eidx;            // destinations
    const int* ej = eidx + N_EDGES;  // sources

    gemm_st   <<<(N_NODES + GR - 1) / GR, 256, 0, stream>>>(x, W, attn, hbuf, s, t, count);
    count_exp <<<NBLK_E, 256, 0, stream>>>(ei, ej, s, t, count, partial, rank, wexp);
    scanA     <<<NBLK_N + 1, 256, 0, stream>>>(count, rowptrL, bsum, partial, zsum);
    scanB     <<<1, 256, 0, stream>>>(bsum, boff, zsum, invZ, rowptrL);
    reorder   <<<NBLK_E, 256, 0, stream>>>(ei, ej, rank, wexp, rowptrL, boff, cv);
    gather_out<<<N_NODES / 4, 256, 0, stream>>>(rowptrL, boff, cv, invZ, hbuf, out);
}